// Round 1
// baseline (411.203 us; speedup 1.0000x reference)
//
#include <hip/hip_runtime.h>
#include <stdint.h>

#define HASH_BITS 19
#define HASH_SIZE (1u << HASH_BITS)

// Items per thread per grid-stride iteration. 4 independent gathers in
// flight per thread (vs 1 before) -> 4x per-wave memory-level parallelism
// for the random table gather, which is the latency-bound path.
#define ILP 4

// Native clang vector types — __builtin_nontemporal_* requires these.
typedef float vfloat2 __attribute__((ext_vector_type(2)));
typedef float vfloat4 __attribute__((ext_vector_type(4)));

// Work item t in [0, 2N): position p = t>>1, half h = t&1.
// Lane pair (2k, 2k+1) fetch the two 16B halves of the same 32B table entry,
// so a wave's gather covers 32 entries with 32B-coalesced transactions.
// positions/out are pure streams -> nontemporal (don't evict table from L2/L3).
// Grid is capped at 2048 persistent-ish blocks (8/CU) and grid-strided:
// removes the 65,536-block launch/retire churn of the 1-item-per-thread form.
__global__ __launch_bounds__(256) void hashgrid2d_kernel(
    const vfloat2* __restrict__ pos,   // N float2
    const vfloat4* __restrict__ table, // HASH_SIZE*2 float4
    vfloat4* __restrict__ out,         // 2N float4
    int n)
{
    const long long nitems = 2LL * (long long)n;
    const long long chunk  = (long long)blockDim.x * ILP;     // items/block/iter
    const long long gstep  = (long long)gridDim.x * chunk;
    // chunk and base are always even -> t&1 == threadIdx.x&1 (static half).
    const uint32_t half = threadIdx.x & 1u;

    for (long long base = (long long)blockIdx.x * chunk; base < nitems;
         base += gstep) {
        if (base + chunk <= nitems) {
            // ---- full tile: batch loads / hashes / gathers / stores ----
            vfloat2 q[ILP];
#pragma unroll
            for (int j = 0; j < ILP; ++j) {
                long long t = base + (long long)j * blockDim.x + threadIdx.x;
                q[j] = __builtin_nontemporal_load(&pos[t >> 1]);
            }

            uint32_t idx[ILP];
#pragma unroll
            for (int j = 0; j < ILP; ++j) {
                // q in [0,4096): float->uint truncation == floor, all hash
                // intermediates stay positive and fit in 64 bits, so uint64
                // arithmetic == reference int64 semantics exactly.
                uint64_t ix = (uint64_t)(uint32_t)q[j].x;
                uint64_t iy = (uint64_t)(uint32_t)q[j].y;
                uint64_t hh = ix;
                hh ^= hh >> 16;
                hh *= 2246822507ull;
                hh ^= hh >> 13;
                hh += iy * 3266489909ull;
                hh ^= hh >> 16;
                idx[j] = (uint32_t)hh & (HASH_SIZE - 1);
            }

            vfloat4 v[ILP];
#pragma unroll
            for (int j = 0; j < ILP; ++j)
                v[j] = table[(size_t)idx[j] * 2 + half];  // keep in L2/L3

#pragma unroll
            for (int j = 0; j < ILP; ++j) {
                long long t = base + (long long)j * blockDim.x + threadIdx.x;
                __builtin_nontemporal_store(v[j], &out[t]);
            }
        } else {
            // ---- tail tile: per-item guard ----
#pragma unroll
            for (int j = 0; j < ILP; ++j) {
                long long t = base + (long long)j * blockDim.x + threadIdx.x;
                if (t < nitems) {
                    vfloat2 q = __builtin_nontemporal_load(&pos[t >> 1]);
                    uint64_t ix = (uint64_t)(uint32_t)q.x;
                    uint64_t iy = (uint64_t)(uint32_t)q.y;
                    uint64_t hh = ix;
                    hh ^= hh >> 16;
                    hh *= 2246822507ull;
                    hh ^= hh >> 13;
                    hh += iy * 3266489909ull;
                    hh ^= hh >> 16;
                    uint32_t idx = (uint32_t)hh & (HASH_SIZE - 1);
                    vfloat4 v = table[(size_t)idx * 2 + half];
                    __builtin_nontemporal_store(v, &out[t]);
                }
            }
        }
    }
}

extern "C" void kernel_launch(void* const* d_in, const int* in_sizes, int n_in,
                              void* d_out, int out_size, void* d_ws, size_t ws_size,
                              hipStream_t stream) {
    const vfloat2* pos   = (const vfloat2*)d_in[0];   // positions [N,2]
    const vfloat4* table = (const vfloat4*)d_in[1];   // table [HASH_SIZE,8]
    vfloat4* out         = (vfloat4*)d_out;           // [N,8] as 2N float4

    int n = in_sizes[0] / 2;  // N positions
    long long nitems = 2LL * n;
    int block = 256;
    long long chunk = (long long)block * ILP;
    long long need = (nitems + chunk - 1) / chunk;
    int grid = (int)(need < 2048 ? need : 2048);
    hashgrid2d_kernel<<<grid, block, 0, stream>>>(pos, table, out, n);
}